// Round 2
// baseline (97.931 us; speedup 1.0000x reference)
//
#include <hip/hip_runtime.h>

#define NHEADS 8
#define NN     128           // nodes per graph
#define NCELL  (NN * NN)     // 16384 floats = 64 KiB
#define NT     256           // threads per block
#define SCALE_F 10.0f

// One block (256 threads, 4 waves) per graph.
// Thread t owns rows 4*rgrp..+4 (rgrp=t>>3, 0..31) and the 16 interleaved
// columns { 4*cgrp + 32*c + e : c in 0..3, e in 0..3 } (cgrp=t&7).
// -> 64 register-resident cells dd[4][16], dd[rr][c*4+e].
// Interleaved column ownership gives:
//   * per-k row-slice read = 4 ds_read_b128 at distinct banks (no padding)
//   * final stores from registers: 8 consecutive lanes (cgrp 0..7) cover a
//     contiguous 128B span of a row -> perfect coalescing, no LDS epilogue.
//
// LDS (64 KiB) time-multiplexed:
//   init/scatter/load: full 128x128 matrix, XOR-swizzled
//        element (i,col) at lds[i*128 + (col ^ ((i&7)<<2))]
//   during FW (matrix dead): rb[2][128] at lds[0..256), cb[2][128] at
//        lds[256..512), reduction scratch at lds[512..528)

__global__ __launch_bounds__(NT)
void spb_fw_kernel(const int* __restrict__ edge_index,
                   const float* __restrict__ edge_weight,
                   const int num_edges, const int epg,
                   float* __restrict__ out)
{
    __shared__ float lds[NCELL];
    const float INF = __builtin_huge_valf();
    const int t    = threadIdx.x;
    const int g    = blockIdx.x;
    const int cgrp = t & 7;
    const int rgrp = t >> 3;           // 0..31

    // ---- Phase 1: init dist matrix (linear writes into swizzled storage) ----
    #pragma unroll
    for (int c = 0; c < 16; ++c) {
        const int m   = t + (c << 8);          // float4 chunk index
        const int i   = m >> 5;
        const int scm = m & 31;
        const int c0  = (scm ^ (i & 7)) << 2;  // logical col base
        float4 v;
        v.x = (c0 + 0 == i) ? 0.0f : INF;
        v.y = (c0 + 1 == i) ? 0.0f : INF;
        v.z = (c0 + 2 == i) ? 0.0f : INF;
        v.w = (c0 + 3 == i) ? 0.0f : INF;
        *reinterpret_cast<float4*>(&lds[m << 2]) = v;
    }
    __syncthreads();

    // ---- Phase 2: scatter edges (atomicMin; positive floats: int order == float order) ----
    const int ebase = g * epg;
    for (int e = t; e < epg; e += NT) {
        const int idx = ebase + e;
        const int src = edge_index[idx];
        const int dst = edge_index[num_edges + idx];
        const float w = edge_weight[idx];
        const int u = src - g * NN;
        const int v = dst - g * NN;
        if (u != v && (unsigned)u < (unsigned)NN && (unsigned)v < (unsigned)NN) {
            const int a = (u << 7) + (v ^ ((u & 7) << 2));
            atomicMin(reinterpret_cast<int*>(&lds[a]), __float_as_int(w));
        }
    }
    __syncthreads();

    // ---- Phase 3: load 64 cells into registers ----
    float dd[4][16];
    #pragma unroll
    for (int rr = 0; rr < 4; ++rr) {
        const int i = (rgrp << 2) + rr;
        const int s = (i & 7) << 2;
        #pragma unroll
        for (int c = 0; c < 4; ++c) {
            const int cc = ((cgrp << 2) + (c << 5)) ^ s;
            float4 v = *reinterpret_cast<const float4*>(&lds[(i << 7) + cc]);
            dd[rr][c*4+0] = v.x; dd[rr][c*4+1] = v.y;
            dd[rr][c*4+2] = v.z; dd[rr][c*4+3] = v.w;
        }
    }
    __syncthreads();   // matrix region dead; buffers may be written

    float* const rb0 = &lds[0];
    float* const rb1 = &lds[128];
    float* const cb0 = &lds[256];
    float* const cb1 = &lds[384];
    float* const red = &lds[512];

    // seed k=0 buffers
    if (rgrp == 0) {   // row 0 = (rgrp=0, rr=0)
        #pragma unroll
        for (int c = 0; c < 4; ++c) {
            float4 v = make_float4(dd[0][c*4], dd[0][c*4+1], dd[0][c*4+2], dd[0][c*4+3]);
            *reinterpret_cast<float4*>(&rb0[(cgrp << 2) + (c << 5)]) = v;
        }
    }
    if (cgrp == 0) {   // col 0 = (cgrp=0, c=0, e=0) -> dd[rr][0]
        float4 v = make_float4(dd[0][0], dd[1][0], dd[2][0], dd[3][0]);
        *reinterpret_cast<float4*>(&cb0[rgrp << 2]) = v;
    }

    // ---- Phase 4: Floyd-Warshall, 1 barrier/k, double-buffered row/col ----
    for (int ko = 0; ko < 8; ++ko) {
        #pragma unroll
        for (int kk = 0; kk < 16; ++kk) {
            const int kn  = (ko << 4) + kk + 1;        // next k (1..128)
            float* const rb  = (kk & 1) ? rb1 : rb0;
            float* const cb  = (kk & 1) ? cb1 : cb0;
            float* const rbn = (kk & 1) ? rb0 : rb1;
            float* const cbn = (kk & 1) ? cb0 : cb1;
            __syncthreads();

            float rk[16];
            #pragma unroll
            for (int c = 0; c < 4; ++c) {
                float4 v = *reinterpret_cast<const float4*>(&rb[(cgrp << 2) + (c << 5)]);
                rk[c*4+0] = v.x; rk[c*4+1] = v.y; rk[c*4+2] = v.z; rk[c*4+3] = v.w;
            }
            float4 c4 = *reinterpret_cast<const float4*>(&cb[rgrp << 2]);
            float ck[4] = {c4.x, c4.y, c4.z, c4.w};

            const int ep = (kk + 1) & 3;    // publish elem / publish row (compile-time)

            // pass 1: cells needed for publishing k+1 (row rr==ep, col elems j&3==ep)
            #pragma unroll
            for (int rr = 0; rr < 4; ++rr)
                #pragma unroll
                for (int j = 0; j < 16; ++j)
                    if (rr == ep || (j & 3) == ep)
                        dd[rr][j] = fminf(dd[rr][j], ck[rr] + rk[j]);

            // publish row kn (global row = 4*rgrp + ep)
            if (rgrp == (kn >> 2)) {
                #pragma unroll
                for (int c = 0; c < 4; ++c) {
                    float4 v = make_float4(dd[ep][c*4], dd[ep][c*4+1],
                                           dd[ep][c*4+2], dd[ep][c*4+3]);
                    *reinterpret_cast<float4*>(&rbn[(cgrp << 2) + (c << 5)]) = v;
                }
            }
            // publish col kn (global col = 4*cgrp + 32*c + ep); kn>>5 is block-uniform
            if (cgrp == ((kn >> 2) & 7)) {
                const int kn5 = kn >> 5;
                if (kn5 == 0) {
                    float4 v = make_float4(dd[0][0*4+ep], dd[1][0*4+ep], dd[2][0*4+ep], dd[3][0*4+ep]);
                    *reinterpret_cast<float4*>(&cbn[rgrp << 2]) = v;
                } else if (kn5 == 1) {
                    float4 v = make_float4(dd[0][1*4+ep], dd[1][1*4+ep], dd[2][1*4+ep], dd[3][1*4+ep]);
                    *reinterpret_cast<float4*>(&cbn[rgrp << 2]) = v;
                } else if (kn5 == 2) {
                    float4 v = make_float4(dd[0][2*4+ep], dd[1][2*4+ep], dd[2][2*4+ep], dd[3][2*4+ep]);
                    *reinterpret_cast<float4*>(&cbn[rgrp << 2]) = v;
                } else if (kn5 == 3) {
                    float4 v = make_float4(dd[0][3*4+ep], dd[1][3*4+ep], dd[2][3*4+ep], dd[3][3*4+ep]);
                    *reinterpret_cast<float4*>(&cbn[rgrp << 2]) = v;
                }
            }

            // pass 2: remaining cells
            #pragma unroll
            for (int rr = 0; rr < 4; ++rr)
                #pragma unroll
                for (int j = 0; j < 16; ++j)
                    if (!(rr == ep || (j & 3) == ep))
                        dd[rr][j] = fminf(dd[rr][j], ck[rr] + rk[j]);
        }
    }
    __syncthreads();

    // ---- Phase 5: per-graph reductions (max finite, global max) ----
    float mF = 0.0f, mA = 0.0f;   // diag==0 guarantees a finite value
    #pragma unroll
    for (int rr = 0; rr < 4; ++rr)
        #pragma unroll
        for (int j = 0; j < 16; ++j) {
            const float v = dd[rr][j];
            mA = fmaxf(mA, v);
            mF = fmaxf(mF, v < INF ? v : 0.0f);
        }
    #pragma unroll
    for (int o = 32; o > 0; o >>= 1) {
        mF = fmaxf(mF, __shfl_xor(mF, o));
        mA = fmaxf(mA, __shfl_xor(mA, o));
    }
    if ((t & 63) == 0) {
        red[((t >> 6) << 1)]     = mF;
        red[((t >> 6) << 1) + 1] = mA;
    }
    __syncthreads();
    mF = red[0]; mA = red[1];
    #pragma unroll
    for (int wv = 1; wv < 4; ++wv) {
        mF = fmaxf(mF, red[wv * 2]);
        mA = fmaxf(mA, red[wv * 2 + 1]);
    }
    const float twoF  = 2.0f * mF;
    const float maxv  = fmaxf((mA == INF) ? twoF : mF, 1e-8f);
    const float nscal = -SCALE_F / maxv;

    // ---- Phase 6: normalize in registers, store 8 heads directly (coalesced) ----
    float* const outg = out + (size_t)g * (NHEADS * NCELL);
    #pragma unroll
    for (int rr = 0; rr < 4; ++rr) {
        const int i = (rgrp << 2) + rr;
        #pragma unroll
        for (int c = 0; c < 4; ++c) {
            float4 v;
            v.x = ((dd[rr][c*4+0] == INF) ? twoF : dd[rr][c*4+0]) * nscal;
            v.y = ((dd[rr][c*4+1] == INF) ? twoF : dd[rr][c*4+1]) * nscal;
            v.z = ((dd[rr][c*4+2] == INF) ? twoF : dd[rr][c*4+2]) * nscal;
            v.w = ((dd[rr][c*4+3] == INF) ? twoF : dd[rr][c*4+3]) * nscal;
            const int o = (i << 7) + (cgrp << 2) + (c << 5);
            #pragma unroll
            for (int h = 0; h < NHEADS; ++h) {
                *reinterpret_cast<float4*>(&outg[h * NCELL + o]) = v;
            }
        }
    }
}

extern "C" void kernel_launch(void* const* d_in, const int* in_sizes, int n_in,
                              void* d_out, int out_size, void* d_ws, size_t ws_size,
                              hipStream_t stream)
{
    const int*   edge_index  = (const int*)d_in[0];
    const float* edge_w      = (const float*)d_in[1];
    const int E    = in_sizes[1];          // 524288
    const int Ntot = in_sizes[2];          // 32768
    const int G    = Ntot / NN;            // 256 graphs
    const int epg  = E / G;                // 2048 edges/graph (contiguous blocks)
    float* out = (float*)d_out;
    spb_fw_kernel<<<G, NT, 0, stream>>>(edge_index, edge_w, E, epg, out);
}

// Round 3
// 74.721 us; speedup vs baseline: 1.3106x; 1.3106x over previous
//
#include <hip/hip_runtime.h>

#define NHEADS 8
#define NN     128
#define NCELL  (NN * NN)       // 16384 floats = 64 KiB
#define NT     512             // 8 waves
#define SCALE_F 10.0f

// Blocked Floyd-Warshall, block size 16, one block (512 thr) per graph.
// Thread t: rgrp=t>>4 (rows 4*rgrp..+4), cgrp=t&15 (cols 4*cgrp+64c+e, c=0..1).
// Matrix register-resident: dd[4][8] (dd[rr][c*4+e]).
// Per block-step kb: extract panels -> wave kb closes diag tile via shfl-FW
// (in-register, no barrier) -> bar -> panel min-plus (all) -> bar -> rank-16
// min-plus update of dd. 2 barriers/step, 16 total (vs 128 in R1).
//
// LDS float offsets (panels swizzled: elem(row,j) at row*128+4*((j>>2)^(row&7))+(j&3)):
#define RP_O 0
#define RP_N 2048
#define CP_O 4096
#define CP_N 6144
#define DP   8192     // D* [16][16]
#define DPT  8448     // D*T: DPT[x*16+y] = D*[y][x]
#define RED  8704

template<int CB>   // CB = 4*(kb>>2): dd column-half holding this block's cols
__device__ __forceinline__ void block_step(float (&dd)[4][8], float* lds,
                                           const int kb, const int t,
                                           const int rgrp, const int cgrp)
{
    // ---- extract panels from registers (pre-A values) ----
    if ((rgrp >> 2) == kb) {                 // row-panel owner
        const int q = rgrp & 3;
        #pragma unroll
        for (int rr = 0; rr < 4; ++rr) {
            const int iloc = 4 * q + rr;
            const int sw = iloc & 7;
            #pragma unroll
            for (int c = 0; c < 2; ++c) {
                float4 v = make_float4(dd[rr][c*4+0], dd[rr][c*4+1],
                                       dd[rr][c*4+2], dd[rr][c*4+3]);
                *reinterpret_cast<float4*>(
                    &lds[RP_O + iloc*128 + (((cgrp + 16*c) ^ sw) << 2)]) = v;
            }
        }
    }
    {
        const int q2 = (cgrp - 4 * kb) & 15;  // col-panel owner iff q2 < 4
        if (q2 < 4) {
            #pragma unroll
            for (int e = 0; e < 4; ++e) {
                const int jj = 4 * q2 + e;
                float4 v = make_float4(dd[0][CB+e], dd[1][CB+e],
                                       dd[2][CB+e], dd[3][CB+e]);
                *reinterpret_cast<float4*>(
                    &lds[CP_O + jj*128 + ((rgrp ^ (jj & 7)) << 2)]) = v;
            }
        }
    }

    // ---- phase A: wave kb closes the 16x16 diagonal tile in-register ----
    if ((t >> 6) == kb) {
        const int l  = t & 63;
        const int ra = l >> 4;
        const int ca = ((l & 15) - 4 * kb) & 15;     // active iff < 4
        const bool act = (ca < 4);
        #pragma unroll
        for (int k = 0; k < 16; ++k) {
            const int kq = k >> 2, ke = k & 3;
            const int lsc = (l & 48) | ((4 * kb + kq) & 15);  // col source
            const int lsr = (kq << 4) | (l & 15);             // row source
            float cv0 = __shfl(dd[0][CB+ke], lsc);
            float cv1 = __shfl(dd[1][CB+ke], lsc);
            float cv2 = __shfl(dd[2][CB+ke], lsc);
            float cv3 = __shfl(dd[3][CB+ke], lsc);
            float rv0 = __shfl(dd[ke][CB+0], lsr);
            float rv1 = __shfl(dd[ke][CB+1], lsr);
            float rv2 = __shfl(dd[ke][CB+2], lsr);
            float rv3 = __shfl(dd[ke][CB+3], lsr);
            if (act) {
                dd[0][CB+0]=fminf(dd[0][CB+0],cv0+rv0); dd[0][CB+1]=fminf(dd[0][CB+1],cv0+rv1);
                dd[0][CB+2]=fminf(dd[0][CB+2],cv0+rv2); dd[0][CB+3]=fminf(dd[0][CB+3],cv0+rv3);
                dd[1][CB+0]=fminf(dd[1][CB+0],cv1+rv0); dd[1][CB+1]=fminf(dd[1][CB+1],cv1+rv1);
                dd[1][CB+2]=fminf(dd[1][CB+2],cv1+rv2); dd[1][CB+3]=fminf(dd[1][CB+3],cv1+rv3);
                dd[2][CB+0]=fminf(dd[2][CB+0],cv2+rv0); dd[2][CB+1]=fminf(dd[2][CB+1],cv2+rv1);
                dd[2][CB+2]=fminf(dd[2][CB+2],cv2+rv2); dd[2][CB+3]=fminf(dd[2][CB+3],cv2+rv3);
                dd[3][CB+0]=fminf(dd[3][CB+0],cv3+rv0); dd[3][CB+1]=fminf(dd[3][CB+1],cv3+rv1);
                dd[3][CB+2]=fminf(dd[3][CB+2],cv3+rv2); dd[3][CB+3]=fminf(dd[3][CB+3],cv3+rv3);
            }
        }
        if (act) {   // publish D* and D*T
            #pragma unroll
            for (int rr = 0; rr < 4; ++rr) {
                float4 v = make_float4(dd[rr][CB+0], dd[rr][CB+1],
                                       dd[rr][CB+2], dd[rr][CB+3]);
                *reinterpret_cast<float4*>(&lds[DP + (4*ra+rr)*16 + 4*ca]) = v;
            }
            #pragma unroll
            for (int e = 0; e < 4; ++e) {
                float4 v = make_float4(dd[0][CB+e], dd[1][CB+e],
                                       dd[2][CB+e], dd[3][CB+e]);
                *reinterpret_cast<float4*>(&lds[DPT + (4*ca+e)*16 + 4*ra]) = v;
            }
        }
    }
    __syncthreads();

    // ---- phase B: R_new = D* (x) R_old ; C_newT = D*T (x) C_oldT ----
    {
        const int a  = t >> 5;    // 0..15 output panel row
        const int ch = t & 31;    // 0..31 float4 chunk
        float da[16], dc[16];
        #pragma unroll
        for (int c = 0; c < 4; ++c) {
            float4 v1 = *reinterpret_cast<const float4*>(&lds[DP  + a*16 + 4*c]);
            float4 v2 = *reinterpret_cast<const float4*>(&lds[DPT + a*16 + 4*c]);
            da[4*c+0]=v1.x; da[4*c+1]=v1.y; da[4*c+2]=v1.z; da[4*c+3]=v1.w;
            dc[4*c+0]=v2.x; dc[4*c+1]=v2.y; dc[4*c+2]=v2.z; dc[4*c+3]=v2.w;
        }
        const float INF = __builtin_huge_valf();
        float aR0=INF,aR1=INF,aR2=INF,aR3=INF, aC0=INF,aC1=INF,aC2=INF,aC3=INF;
        #pragma unroll
        for (int k = 0; k < 16; ++k) {
            const int off = k*128 + (((ch) ^ (k & 7)) << 2);
            float4 r4 = *reinterpret_cast<const float4*>(&lds[RP_O + off]);
            float4 c4 = *reinterpret_cast<const float4*>(&lds[CP_O + off]);
            aR0 = fminf(aR0, da[k] + r4.x); aR1 = fminf(aR1, da[k] + r4.y);
            aR2 = fminf(aR2, da[k] + r4.z); aR3 = fminf(aR3, da[k] + r4.w);
            aC0 = fminf(aC0, dc[k] + c4.x); aC1 = fminf(aC1, dc[k] + c4.y);
            aC2 = fminf(aC2, dc[k] + c4.z); aC3 = fminf(aC3, dc[k] + c4.w);
        }
        const int offo = a*128 + ((ch ^ (a & 7)) << 2);
        *reinterpret_cast<float4*>(&lds[RP_N + offo]) = make_float4(aR0,aR1,aR2,aR3);
        *reinterpret_cast<float4*>(&lds[CP_N + offo]) = make_float4(aC0,aC1,aC2,aC3);
    }
    __syncthreads();

    // ---- phase C: dd = min(dd, C_new[i][k] + R_new[k][j]) over 16 k ----
    #pragma unroll
    for (int kp = 0; kp < 8; ++kp) {
        const int k0 = 2*kp, k1 = 2*kp + 1;
        float4 cp0 = *reinterpret_cast<const float4*>(&lds[CP_N + k0*128 + ((rgrp       ^ (k0&7)) << 2)]);
        float4 r0a = *reinterpret_cast<const float4*>(&lds[RP_N + k0*128 + ((cgrp       ^ (k0&7)) << 2)]);
        float4 r0b = *reinterpret_cast<const float4*>(&lds[RP_N + k0*128 + (((cgrp+16)  ^ (k0&7)) << 2)]);
        float4 cp1 = *reinterpret_cast<const float4*>(&lds[CP_N + k1*128 + ((rgrp       ^ (k1&7)) << 2)]);
        float4 r1a = *reinterpret_cast<const float4*>(&lds[RP_N + k1*128 + ((cgrp       ^ (k1&7)) << 2)]);
        float4 r1b = *reinterpret_cast<const float4*>(&lds[RP_N + k1*128 + (((cgrp+16)  ^ (k1&7)) << 2)]);
        const float c0[4] = {cp0.x, cp0.y, cp0.z, cp0.w};
        const float c1[4] = {cp1.x, cp1.y, cp1.z, cp1.w};
        const float ra0[4] = {r0a.x, r0a.y, r0a.z, r0a.w};
        const float rb0[4] = {r0b.x, r0b.y, r0b.z, r0b.w};
        const float ra1[4] = {r1a.x, r1a.y, r1a.z, r1a.w};
        const float rb1[4] = {r1b.x, r1b.y, r1b.z, r1b.w};
        #pragma unroll
        for (int rr = 0; rr < 4; ++rr) {
            #pragma unroll
            for (int e = 0; e < 4; ++e) {
                dd[rr][e]   = fminf(fminf(dd[rr][e],   c0[rr] + ra0[e]), c1[rr] + ra1[e]);
                dd[rr][4+e] = fminf(fminf(dd[rr][4+e], c0[rr] + rb0[e]), c1[rr] + rb1[e]);
            }
        }
    }
}

__global__ __launch_bounds__(NT)
void spb_fw_kernel(const int* __restrict__ edge_index,
                   const float* __restrict__ edge_weight,
                   const int num_edges, const int epg,
                   float* __restrict__ out)
{
    __shared__ float lds[NCELL];
    const float INF = __builtin_huge_valf();
    const int t    = threadIdx.x;
    const int g    = blockIdx.x;
    const int cgrp = t & 15;
    const int rgrp = t >> 4;

    // ---- init matrix (swizzled: elem(i,col) at i*128 + (col ^ ((i&7)<<2))) ----
    #pragma unroll
    for (int c = 0; c < 8; ++c) {
        const int m   = t + (c << 9);
        const int i   = m >> 5;
        const int scm = m & 31;
        const int c0  = (scm ^ (i & 7)) << 2;
        float4 v;
        v.x = (c0 + 0 == i) ? 0.0f : INF;
        v.y = (c0 + 1 == i) ? 0.0f : INF;
        v.z = (c0 + 2 == i) ? 0.0f : INF;
        v.w = (c0 + 3 == i) ? 0.0f : INF;
        *reinterpret_cast<float4*>(&lds[m << 2]) = v;
    }
    __syncthreads();

    // ---- scatter edges ----
    const int ebase = g * epg;
    for (int e = t; e < epg; e += NT) {
        const int idx = ebase + e;
        const int src = edge_index[idx];
        const int dst = edge_index[num_edges + idx];
        const float w = edge_weight[idx];
        const int u = src - g * NN;
        const int v = dst - g * NN;
        if (u != v && (unsigned)u < (unsigned)NN && (unsigned)v < (unsigned)NN) {
            const int a = (u << 7) + (v ^ ((u & 7) << 2));
            atomicMin(reinterpret_cast<int*>(&lds[a]), __float_as_int(w));
        }
    }
    __syncthreads();

    // ---- load matrix into registers: dd[rr][c*4+e] = d[4rgrp+rr][4cgrp+64c+e] ----
    float dd[4][8];
    #pragma unroll
    for (int rr = 0; rr < 4; ++rr) {
        const int i = (rgrp << 2) + rr;
        const int s = i & 7;
        #pragma unroll
        for (int c = 0; c < 2; ++c) {
            float4 v = *reinterpret_cast<const float4*>(
                &lds[(i << 7) + (((cgrp + 16*c) ^ s) << 2)]);
            dd[rr][c*4+0]=v.x; dd[rr][c*4+1]=v.y; dd[rr][c*4+2]=v.z; dd[rr][c*4+3]=v.w;
        }
    }
    __syncthreads();   // matrix region dead; panels may be written

    // ---- 8 block-steps ----
    #pragma unroll
    for (int kbl = 0; kbl < 4; ++kbl)
        block_step<0>(dd, lds, kbl, t, rgrp, cgrp);
    #pragma unroll
    for (int kbl = 0; kbl < 4; ++kbl)
        block_step<4>(dd, lds, 4 + kbl, t, rgrp, cgrp);

    // ---- reductions ----
    float mF = 0.0f, mA = 0.0f;
    #pragma unroll
    for (int rr = 0; rr < 4; ++rr)
        #pragma unroll
        for (int j = 0; j < 8; ++j) {
            const float v = dd[rr][j];
            mA = fmaxf(mA, v);
            mF = fmaxf(mF, v < INF ? v : 0.0f);
        }
    #pragma unroll
    for (int o = 32; o > 0; o >>= 1) {
        mF = fmaxf(mF, __shfl_xor(mF, o));
        mA = fmaxf(mA, __shfl_xor(mA, o));
    }
    if ((t & 63) == 0) {
        lds[RED + ((t >> 6) << 1)]     = mF;
        lds[RED + ((t >> 6) << 1) + 1] = mA;
    }
    __syncthreads();
    mF = lds[RED]; mA = lds[RED + 1];
    #pragma unroll
    for (int wv = 1; wv < 8; ++wv) {
        mF = fmaxf(mF, lds[RED + wv*2]);
        mA = fmaxf(mA, lds[RED + wv*2 + 1]);
    }
    const float twoF  = 2.0f * mF;
    const float maxv  = fmaxf((mA == INF) ? twoF : mF, 1e-8f);
    const float nscal = -SCALE_F / maxv;

    // ---- normalize in registers, store 8 heads (coalesced 256B runs) ----
    float* const outg = out + (size_t)g * (NHEADS * NCELL);
    #pragma unroll
    for (int rr = 0; rr < 4; ++rr) {
        const int i = (rgrp << 2) + rr;
        #pragma unroll
        for (int c = 0; c < 2; ++c) {
            float4 v;
            v.x = ((dd[rr][c*4+0] == INF) ? twoF : dd[rr][c*4+0]) * nscal;
            v.y = ((dd[rr][c*4+1] == INF) ? twoF : dd[rr][c*4+1]) * nscal;
            v.z = ((dd[rr][c*4+2] == INF) ? twoF : dd[rr][c*4+2]) * nscal;
            v.w = ((dd[rr][c*4+3] == INF) ? twoF : dd[rr][c*4+3]) * nscal;
            const int o = (i << 7) + (cgrp << 2) + (c << 6);
            #pragma unroll
            for (int h = 0; h < NHEADS; ++h) {
                *reinterpret_cast<float4*>(&outg[h * NCELL + o]) = v;
            }
        }
    }
}

extern "C" void kernel_launch(void* const* d_in, const int* in_sizes, int n_in,
                              void* d_out, int out_size, void* d_ws, size_t ws_size,
                              hipStream_t stream)
{
    const int*   edge_index  = (const int*)d_in[0];
    const float* edge_w      = (const float*)d_in[1];
    const int E    = in_sizes[1];
    const int Ntot = in_sizes[2];
    const int G    = Ntot / NN;
    const int epg  = E / G;
    float* out = (float*)d_out;
    spb_fw_kernel<<<G, NT, 0, stream>>>(edge_index, edge_w, E, epg, out);
}

// Round 5
// 68.798 us; speedup vs baseline: 1.4235x; 1.0861x over previous
//
#include <hip/hip_runtime.h>

#define NHEADS 8
#define NN     128
#define NCELL  (NN * NN)       // 16384 floats = 64 KiB
#define NT     512             // 8 waves
#define SCALE_F 10.0f

typedef float nfloat4 __attribute__((ext_vector_type(4)));

// Blocked Floyd-Warshall, B=16, one block (512 thr) per graph.
// Thread t: rgrp=t>>4 (rows 4rgrp..+4), cgrp=t&15 (cols 4cgrp+64c+e, c=0..1).
// dd[4][8] register-resident. Per step kb:
//   extract panels+diag -> wave kb closes 16x16 tile via readlane-FW -> bar
//   -> phase B (panel min-plus, split R/C across half-waves) -> bar
//   -> phase C (rank-16 update of dd). 2 barriers/step.
//
// LDS float offsets (panels swizzled: elem(row,j) at row*128+4*((j>>2)^(row&7))+(j&3)):
#define RP_O 0
#define RP_N 2048
#define CP_O 4096
#define CP_N 6144
#define DP   8192     // diag tile / D* [16][16]
#define DPT  8448     // D*T
#define RED  8704

template<int CB>   // CB = 4*(kb>>2): dd column-half holding this block's cols
__device__ __forceinline__ void block_step(float (&dd)[4][8], float* lds,
                                           const int kb, const int t,
                                           const int rgrp, const int cgrp)
{
    const float INF = __builtin_huge_valf();

    // ---- extract row/col panels (pre-step values) ----
    if ((rgrp >> 2) == kb) {                 // row-panel owners = wave kb
        const int q = rgrp & 3;
        #pragma unroll
        for (int rr = 0; rr < 4; ++rr) {
            const int iloc = 4 * q + rr;
            const int sw = iloc & 7;
            #pragma unroll
            for (int c = 0; c < 2; ++c) {
                float4 v = make_float4(dd[rr][c*4+0], dd[rr][c*4+1],
                                       dd[rr][c*4+2], dd[rr][c*4+3]);
                *reinterpret_cast<float4*>(
                    &lds[RP_O + iloc*128 + (((cgrp + 16*c) ^ sw) << 2)]) = v;
            }
        }
    }
    {
        const int q2 = (cgrp - 4 * kb) & 15;  // col-panel owner iff q2 < 4
        if (q2 < 4) {
            #pragma unroll
            for (int e = 0; e < 4; ++e) {
                const int jj = 4 * q2 + e;
                float4 v = make_float4(dd[0][CB+e], dd[1][CB+e],
                                       dd[2][CB+e], dd[3][CB+e]);
                *reinterpret_cast<float4*>(
                    &lds[CP_O + jj*128 + ((rgrp ^ (jj & 7)) << 2)]) = v;
            }
        }
    }

    // ---- phase A: wave kb -- dump diag tile to LDS, readlane-closure ----
    if ((t >> 6) == kb) {
        const int l = t & 63;
        const int p = cgrp - 4 * (kb & 3);
        if ((unsigned)p < 4u) {              // diag-tile owner (16 thr, all in wave kb)
            const int q = rgrp & 3;
            #pragma unroll
            for (int rr = 0; rr < 4; ++rr) {
                *reinterpret_cast<float4*>(&lds[DP + (4*q+rr)*16 + 4*p]) =
                    make_float4(dd[rr][CB+0], dd[rr][CB+1], dd[rr][CB+2], dd[rr][CB+3]);
            }
        }
        asm volatile("s_waitcnt lgkmcnt(0)" ::: "memory");
        // every lane loads row (l&15) -> 4x duplicated, all defined
        float T[16];
        const int lr = l & 15;
        #pragma unroll
        for (int c4 = 0; c4 < 4; ++c4) {
            float4 v = *reinterpret_cast<const float4*>(&lds[DP + lr*16 + 4*c4]);
            T[c4*4+0]=v.x; T[c4*4+1]=v.y; T[c4*4+2]=v.z; T[c4*4+3]=v.w;
        }
        #pragma unroll
        for (int k = 0; k < 16; ++k) {
            float rk[16];
            #pragma unroll
            for (int j = 0; j < 16; ++j)
                rk[j] = __int_as_float(
                    __builtin_amdgcn_readlane(__float_as_int(T[j]), k));
            const float dik = T[k];
            #pragma unroll
            for (int j = 0; j < 16; ++j)
                T[j] = fminf(T[j], dik + rk[j]);
        }
        if (l < 16) {   // publish D* and D*T
            #pragma unroll
            for (int c4 = 0; c4 < 4; ++c4)
                *reinterpret_cast<float4*>(&lds[DP + l*16 + 4*c4]) =
                    make_float4(T[c4*4], T[c4*4+1], T[c4*4+2], T[c4*4+3]);
            #pragma unroll
            for (int j = 0; j < 16; ++j)
                lds[DPT + j*16 + l] = T[j];
        }
    }
    __syncthreads();

    // ---- phase B: R_new = D* (x) R_old ; C_newT = D*T (x) C_oldT ----
    // thread = (ap = wave -> rows {2ap,2ap+1}, half-wave = panel, ch = chunk)
    {
        const int ap = t >> 6;
        const int ch = t & 31;
        const int isC   = (t >> 5) & 1;
        const int base  = isC ? CP_O : RP_O;
        const int dbase = isC ? DPT  : DP;
        const int obase = isC ? CP_N : RP_N;
        float d0[16], d1[16];
        #pragma unroll
        for (int c4 = 0; c4 < 4; ++c4) {
            float4 v0 = *reinterpret_cast<const float4*>(&lds[dbase + (2*ap  )*16 + 4*c4]);
            float4 v1 = *reinterpret_cast<const float4*>(&lds[dbase + (2*ap+1)*16 + 4*c4]);
            d0[c4*4+0]=v0.x; d0[c4*4+1]=v0.y; d0[c4*4+2]=v0.z; d0[c4*4+3]=v0.w;
            d1[c4*4+0]=v1.x; d1[c4*4+1]=v1.y; d1[c4*4+2]=v1.z; d1[c4*4+3]=v1.w;
        }
        float a00=INF,a01=INF,a02=INF,a03=INF;
        float a10=INF,a11=INF,a12=INF,a13=INF;
        #pragma unroll
        for (int k = 0; k < 16; ++k) {
            float4 r = *reinterpret_cast<const float4*>(
                &lds[base + k*128 + ((ch ^ (k & 7)) << 2)]);
            a00=fminf(a00,d0[k]+r.x); a01=fminf(a01,d0[k]+r.y);
            a02=fminf(a02,d0[k]+r.z); a03=fminf(a03,d0[k]+r.w);
            a10=fminf(a10,d1[k]+r.x); a11=fminf(a11,d1[k]+r.y);
            a12=fminf(a12,d1[k]+r.z); a13=fminf(a13,d1[k]+r.w);
        }
        *reinterpret_cast<float4*>(
            &lds[obase + (2*ap  )*128 + ((ch ^ ((2*ap  ) & 7)) << 2)]) =
            make_float4(a00,a01,a02,a03);
        *reinterpret_cast<float4*>(
            &lds[obase + (2*ap+1)*128 + ((ch ^ ((2*ap+1) & 7)) << 2)]) =
            make_float4(a10,a11,a12,a13);
    }
    __syncthreads();

    // ---- phase C: dd = min(dd, C_new[i][k] + R_new[k][j]) over 16 k ----
    #pragma unroll
    for (int kp = 0; kp < 8; ++kp) {
        const int k0 = 2*kp, k1 = 2*kp + 1;
        float4 cp0 = *reinterpret_cast<const float4*>(&lds[CP_N + k0*128 + ((rgrp      ^ (k0&7)) << 2)]);
        float4 r0a = *reinterpret_cast<const float4*>(&lds[RP_N + k0*128 + ((cgrp      ^ (k0&7)) << 2)]);
        float4 r0b = *reinterpret_cast<const float4*>(&lds[RP_N + k0*128 + (((cgrp+16) ^ (k0&7)) << 2)]);
        float4 cp1 = *reinterpret_cast<const float4*>(&lds[CP_N + k1*128 + ((rgrp      ^ (k1&7)) << 2)]);
        float4 r1a = *reinterpret_cast<const float4*>(&lds[RP_N + k1*128 + ((cgrp      ^ (k1&7)) << 2)]);
        float4 r1b = *reinterpret_cast<const float4*>(&lds[RP_N + k1*128 + (((cgrp+16) ^ (k1&7)) << 2)]);
        const float c0[4]  = {cp0.x, cp0.y, cp0.z, cp0.w};
        const float c1[4]  = {cp1.x, cp1.y, cp1.z, cp1.w};
        const float ra0[4] = {r0a.x, r0a.y, r0a.z, r0a.w};
        const float rb0[4] = {r0b.x, r0b.y, r0b.z, r0b.w};
        const float ra1[4] = {r1a.x, r1a.y, r1a.z, r1a.w};
        const float rb1[4] = {r1b.x, r1b.y, r1b.z, r1b.w};
        #pragma unroll
        for (int rr = 0; rr < 4; ++rr) {
            #pragma unroll
            for (int e = 0; e < 4; ++e) {
                dd[rr][e]   = fminf(fminf(dd[rr][e],   c0[rr] + ra0[e]), c1[rr] + ra1[e]);
                dd[rr][4+e] = fminf(fminf(dd[rr][4+e], c0[rr] + rb0[e]), c1[rr] + rb1[e]);
            }
        }
    }
}

__global__ __launch_bounds__(NT)
void spb_fw_kernel(const int* __restrict__ edge_index,
                   const float* __restrict__ edge_weight,
                   const int num_edges, const int epg,
                   float* __restrict__ out)
{
    __shared__ float lds[NCELL];
    const float INF = __builtin_huge_valf();
    const int t    = threadIdx.x;
    const int g    = blockIdx.x;
    const int cgrp = t & 15;
    const int rgrp = t >> 4;

    // ---- init matrix (swizzled: elem(i,col) at i*128 + (col ^ ((i&7)<<2))) ----
    #pragma unroll
    for (int c = 0; c < 8; ++c) {
        const int m   = t + (c << 9);
        const int i   = m >> 5;
        const int scm = m & 31;
        const int c0  = (scm ^ (i & 7)) << 2;
        float4 v;
        v.x = (c0 + 0 == i) ? 0.0f : INF;
        v.y = (c0 + 1 == i) ? 0.0f : INF;
        v.z = (c0 + 2 == i) ? 0.0f : INF;
        v.w = (c0 + 3 == i) ? 0.0f : INF;
        *reinterpret_cast<float4*>(&lds[m << 2]) = v;
    }
    __syncthreads();

    // ---- scatter edges ----
    const int ebase = g * epg;
    for (int e = t; e < epg; e += NT) {
        const int idx = ebase + e;
        const int src = edge_index[idx];
        const int dst = edge_index[num_edges + idx];
        const float w = edge_weight[idx];
        const int u = src - g * NN;
        const int v = dst - g * NN;
        if (u != v && (unsigned)u < (unsigned)NN && (unsigned)v < (unsigned)NN) {
            const int a = (u << 7) + (v ^ ((u & 7) << 2));
            atomicMin(reinterpret_cast<int*>(&lds[a]), __float_as_int(w));
        }
    }
    __syncthreads();

    // ---- load matrix into registers: dd[rr][c*4+e] = d[4rgrp+rr][4cgrp+64c+e] ----
    float dd[4][8];
    #pragma unroll
    for (int rr = 0; rr < 4; ++rr) {
        const int i = (rgrp << 2) + rr;
        const int s = i & 7;
        #pragma unroll
        for (int c = 0; c < 2; ++c) {
            float4 v = *reinterpret_cast<const float4*>(
                &lds[(i << 7) + (((cgrp + 16*c) ^ s) << 2)]);
            dd[rr][c*4+0]=v.x; dd[rr][c*4+1]=v.y; dd[rr][c*4+2]=v.z; dd[rr][c*4+3]=v.w;
        }
    }
    __syncthreads();   // matrix region dead; panels may be written

    // ---- 8 block-steps ----
    #pragma unroll
    for (int kbl = 0; kbl < 4; ++kbl)
        block_step<0>(dd, lds, kbl, t, rgrp, cgrp);
    #pragma unroll
    for (int kbl = 0; kbl < 4; ++kbl)
        block_step<4>(dd, lds, 4 + kbl, t, rgrp, cgrp);

    // ---- reductions ----
    float mF = 0.0f, mA = 0.0f;
    #pragma unroll
    for (int rr = 0; rr < 4; ++rr)
        #pragma unroll
        for (int j = 0; j < 8; ++j) {
            const float v = dd[rr][j];
            mA = fmaxf(mA, v);
            mF = fmaxf(mF, v < INF ? v : 0.0f);
        }
    #pragma unroll
    for (int o = 32; o > 0; o >>= 1) {
        mF = fmaxf(mF, __shfl_xor(mF, o));
        mA = fmaxf(mA, __shfl_xor(mA, o));
    }
    if ((t & 63) == 0) {
        lds[RED + ((t >> 6) << 1)]     = mF;
        lds[RED + ((t >> 6) << 1) + 1] = mA;
    }
    __syncthreads();
    mF = lds[RED]; mA = lds[RED + 1];
    #pragma unroll
    for (int wv = 1; wv < 8; ++wv) {
        mF = fmaxf(mF, lds[RED + wv*2]);
        mA = fmaxf(mA, lds[RED + wv*2 + 1]);
    }
    const float twoF  = 2.0f * mF;
    const float maxv  = fmaxf((mA == INF) ? twoF : mF, 1e-8f);
    const float nscal = -SCALE_F / maxv;

    // ---- normalize in registers, store 8 heads (coalesced, nontemporal) ----
    float* const outg = out + (size_t)g * (NHEADS * NCELL);
    #pragma unroll
    for (int rr = 0; rr < 4; ++rr) {
        const int i = (rgrp << 2) + rr;
        #pragma unroll
        for (int c = 0; c < 2; ++c) {
            nfloat4 v;
            v.x = ((dd[rr][c*4+0] == INF) ? twoF : dd[rr][c*4+0]) * nscal;
            v.y = ((dd[rr][c*4+1] == INF) ? twoF : dd[rr][c*4+1]) * nscal;
            v.z = ((dd[rr][c*4+2] == INF) ? twoF : dd[rr][c*4+2]) * nscal;
            v.w = ((dd[rr][c*4+3] == INF) ? twoF : dd[rr][c*4+3]) * nscal;
            const int o = (i << 7) + (cgrp << 2) + (c << 6);
            #pragma unroll
            for (int h = 0; h < NHEADS; ++h) {
                __builtin_nontemporal_store(
                    v, reinterpret_cast<nfloat4*>(&outg[h * NCELL + o]));
            }
        }
    }
}

extern "C" void kernel_launch(void* const* d_in, const int* in_sizes, int n_in,
                              void* d_out, int out_size, void* d_ws, size_t ws_size,
                              hipStream_t stream)
{
    const int*   edge_index  = (const int*)d_in[0];
    const float* edge_w      = (const float*)d_in[1];
    const int E    = in_sizes[1];
    const int Ntot = in_sizes[2];
    const int G    = Ntot / NN;
    const int epg  = E / G;
    float* out = (float*)d_out;
    spb_fw_kernel<<<G, NT, 0, stream>>>(edge_index, edge_w, E, epg, out);
}